// Round 1
// baseline (84.652 us; speedup 1.0000x reference)
//
#include <hip/hip_runtime.h>

#define T_TOK 65536
#define DDIM 512
#define NEXP 8
#define CAP 16384
#define PADX 132  // 128 + 4 pad: stride 132 floats = 528B = 33*16B (aligned), banks (4*l+d)%32 even

__device__ inline float wave_sum(float v) {
#pragma unroll
  for (int m = 1; m < 64; m <<= 1) v += __shfl_xor(v, m, 64);
  return v;
}

// --- K0a: w2s[e*H+h] = sum_d W2[e,h,d]; one wave per row, 4096 rows ---
__global__ void k_w2s(const float* __restrict__ W2, float* __restrict__ w2s) {
  int w = threadIdx.x >> 6, lane = threadIdx.x & 63;
  int row = blockIdx.x * 4 + w;  // < 4096
  const float* p = W2 + (size_t)row * 512;
  float sum = 0.f;
#pragma unroll
  for (int j = 0; j < 8; ++j) sum += p[lane + j * 64];
  sum = wave_sum(sum);
  if (lane == 0) w2s[row] = sum;
}

// --- K0b: vT[d*8+e] = sum_h W1[e,d,h]*w2s[e,h]; last block computes beta[e] ---
__global__ void k_v_beta(const float* __restrict__ W1, const float* __restrict__ b1,
                         const float* __restrict__ b2, const float* __restrict__ w2s,
                         float* __restrict__ vT, float* __restrict__ beta) {
  int w = threadIdx.x >> 6, lane = threadIdx.x & 63;
  if (blockIdx.x < 1024) {
    int rid = blockIdx.x * 4 + w;  // rid = e*512 + d
    int e = rid >> 9, d = rid & 511;
    const float* p = W1 + (size_t)rid * 512;
    const float* q = w2s + e * 512;
    float sum = 0.f;
#pragma unroll
    for (int j = 0; j < 8; ++j) { int h = lane + j * 64; sum += p[h] * q[h]; }
    sum = wave_sum(sum);
    if (lane == 0) vT[d * 8 + e] = sum;
  } else {
    // beta[e] = sum_h b1[e,h]*w2s[e,h] + sum_d b2[e,d]
#pragma unroll
    for (int r = 0; r < 2; ++r) {
      int e = w + r * 4;
      float sum = 0.f;
#pragma unroll
      for (int j = 0; j < 8; ++j) {
        int i = lane + j * 64;
        sum += b1[e * 512 + i] * w2s[e * 512 + i] + b2[e * 512 + i];
      }
      sum = wave_sum(sum);
      if (lane == 0) beta[e] = sum;
    }
  }
}

// --- K1: per token 16 dots: [0..7]=x·Wg (logits), [8..15]=x·v. 64 tokens/block,
// token-per-lane; wave w owns 4 of the 16 outputs (uniform weight loads, no reduction).
__global__ __launch_bounds__(256, 4) void k_dots(const float* __restrict__ x,
                                                 const float* __restrict__ Wg,
                                                 const float* __restrict__ vT,
                                                 float* __restrict__ dots) {
  __shared__ float sX[64 * PADX];  // 33792 B -> 4 blocks/CU
  int tid = threadIdx.x;
  int lane = tid & 63;
  int wu = __builtin_amdgcn_readfirstlane(tid >> 6);  // force SGPR -> scalar loads
  const float* Pq = (wu < 2) ? Wg : vT;               // both laid out [d][8]
  int qb = (wu & 1) * 4;
  int t0 = blockIdx.x * 64;
  float a0 = 0.f, a1 = 0.f, a2 = 0.f, a3 = 0.f;
  for (int c = 0; c < 4; ++c) {  // 4 chunks of 128 dims
    if (c) __syncthreads();
    // stage 64 tokens x 128 floats, coalesced
#pragma unroll
    for (int r = 0; r < 8; ++r) {
      int f = tid + r * 256;          // < 2048 float4s
      int tok = f >> 5;               // 32 float4 per token
      int dl = (f & 31) * 4;
      float4 val = *reinterpret_cast<const float4*>(
          x + (size_t)(t0 + tok) * 512 + c * 128 + dl);
      *reinterpret_cast<float4*>(&sX[tok * PADX + dl]) = val;
    }
    __syncthreads();
    const float* xrow = &sX[lane * PADX];
#pragma unroll 8
    for (int dd = 0; dd < 128; dd += 4) {
      float4 xv = *reinterpret_cast<const float4*>(xrow + dd);
      int dg = c * 128 + dd;
      float4 u0 = *reinterpret_cast<const float4*>(Pq + (size_t)(dg + 0) * 8 + qb);
      float4 u1 = *reinterpret_cast<const float4*>(Pq + (size_t)(dg + 1) * 8 + qb);
      float4 u2 = *reinterpret_cast<const float4*>(Pq + (size_t)(dg + 2) * 8 + qb);
      float4 u3 = *reinterpret_cast<const float4*>(Pq + (size_t)(dg + 3) * 8 + qb);
      a0 += xv.x * u0.x + xv.y * u1.x + xv.z * u2.x + xv.w * u3.x;
      a1 += xv.x * u0.y + xv.y * u1.y + xv.z * u2.y + xv.w * u3.y;
      a2 += xv.x * u0.z + xv.y * u1.z + xv.z * u2.z + xv.w * u3.z;
      a3 += xv.x * u0.w + xv.y * u1.w + xv.z * u2.w + xv.w * u3.w;
    }
  }
  float4 o; o.x = a0; o.y = a1; o.z = a2; o.w = a3;
  *reinterpret_cast<float4*>(dots + (size_t)(t0 + lane) * 16 + wu * 4) = o;
}

// --- K2a: top-2 select + renorm weights + per-block expert histograms ---
__global__ void k_top2(const float* __restrict__ dots, const float* __restrict__ beta,
                       float4* __restrict__ wd, int* __restrict__ epk,
                       int* __restrict__ hist) {
  __shared__ int c0[8], c1[8];
  int tid = threadIdx.x;
  if (tid < 8) { c0[tid] = 0; c1[tid] = 0; }
  __syncthreads();
  int t = blockIdx.x * 256 + tid;
  const float* p = dots + (size_t)t * 16;
  float l[8], dv[8];
#pragma unroll
  for (int e = 0; e < 8; ++e) { l[e] = p[e]; dv[e] = p[8 + e]; }
  int e1 = 0; float v1 = l[0];
#pragma unroll
  for (int e = 1; e < 8; ++e) if (l[e] > v1) { v1 = l[e]; e1 = e; }  // ties -> low idx
  int e2 = 0; float v2 = -3.4e38f;
#pragma unroll
  for (int e = 0; e < 8; ++e) if (e != e1 && l[e] > v2) { v2 = l[e]; e2 = e; }
  float wexp = expf(v2 - v1);           // g2/g1 after softmax; renorm over top-2
  float w1 = 1.f / (1.f + wexp);
  float w2 = wexp * w1;
  float d1 = 0.f, d2 = 0.f;
#pragma unroll
  for (int e = 0; e < 8; ++e) {
    d1 = (e == e1) ? dv[e] : d1;
    d2 = (e == e2) ? dv[e] : d2;
  }
  float4 o; o.x = w1; o.y = w2; o.z = d1 + beta[e1]; o.w = d2 + beta[e2];
  wd[t] = o;
  epk[t] = e1 | (e2 << 8);
  atomicAdd(&c0[e1], 1);
  atomicAdd(&c1[e2], 1);
  __syncthreads();
  if (tid < 8) {
    hist[blockIdx.x * 8 + tid] = c0[tid];
    hist[(256 + blockIdx.x) * 8 + tid] = c1[tid];
  }
}

// --- K2b: exclusive scan of 512 block-histograms (k-major order), per expert ---
__global__ void k_scan(const int* __restrict__ hist, int* __restrict__ off) {
  __shared__ int sH[4096];
  __shared__ int sT[256];
  int tid = threadIdx.x;
  for (int i = tid; i < 4096; i += 256) sH[i] = hist[i];
  __syncthreads();
  int e = tid & 7, g = tid >> 3;  // g < 32, each scans 16 rows
  int run = 0;
  for (int i = g * 16; i < g * 16 + 16; ++i) {
    int cv = sH[i * 8 + e]; sH[i * 8 + e] = run; run += cv;
  }
  sT[g * 8 + e] = run;
  __syncthreads();
  if (tid < 8) {
    int run2 = 0;
    for (int g2 = 0; g2 < 32; ++g2) {
      int cv = sT[g2 * 8 + tid]; sT[g2 * 8 + tid] = run2; run2 += cv;
    }
  }
  __syncthreads();
  int add = sT[g * 8 + e];
  for (int i = g * 16; i < g * 16 + 16; ++i) sH[i * 8 + e] += add;
  __syncthreads();
  for (int i = tid; i < 4096; i += 256) off[i] = sH[i];
}

// --- K2c: stable intra-block ranks via ballots -> pos -> keep -> s[t] ---
__global__ void k_keep(const int* __restrict__ epk, const float4* __restrict__ wd,
                       const int* __restrict__ off, float* __restrict__ s) {
  __shared__ int sC0[32], sC1[32];
  int tid = threadIdx.x, lane = tid & 63, w = tid >> 6;
  int t = blockIdx.x * 256 + tid;
  int ep = epk[t]; int e1 = ep & 255, e2 = ep >> 8;
  unsigned long long lt = (1ull << lane) - 1ull;
  int wr0 = 0, wr1 = 0;
#pragma unroll
  for (int e = 0; e < 8; ++e) {
    unsigned long long m0 = __ballot(e1 == e);
    unsigned long long m1 = __ballot(e2 == e);
    if (e == e1) wr0 = __popcll(m0 & lt);
    if (e == e2) wr1 = __popcll(m1 & lt);
    if (lane == 0) { sC0[w * 8 + e] = __popcll(m0); sC1[w * 8 + e] = __popcll(m1); }
  }
  __syncthreads();
  int woff0 = 0, woff1 = 0;
  for (int wp = 0; wp < 4; ++wp) {
    if (wp < w) { woff0 += sC0[wp * 8 + e1]; woff1 += sC1[wp * 8 + e2]; }
  }
  int b = blockIdx.x;
  int pos0 = off[b * 8 + e1] + woff0 + wr0;
  int pos1 = off[(256 + b) * 8 + e2] + woff1 + wr1;
  float4 v = wd[t];
  float sv = 0.f;
  if (pos0 < CAP) sv += v.x * v.z;
  if (pos1 < CAP) sv += v.y * v.w;
  s[t] = sv;
}

// --- K3: per-row (B=8 rows of N=8192) log_softmax ---
__global__ __launch_bounds__(1024) void k_lsm(const float* __restrict__ s,
                                              float* __restrict__ out) {
  __shared__ float sRa[16], sRb[16];
  int tid = threadIdx.x, lane = tid & 63, w = tid >> 6;
  size_t base = (size_t)blockIdx.x * 8192;
  float v[8];
#pragma unroll
  for (int j = 0; j < 8; ++j) v[j] = s[base + tid + j * 1024];
  float mx = v[0];
#pragma unroll
  for (int j = 1; j < 8; ++j) mx = fmaxf(mx, v[j]);
#pragma unroll
  for (int m = 1; m < 64; m <<= 1) mx = fmaxf(mx, __shfl_xor(mx, m, 64));
  if (lane == 0) sRa[w] = mx;
  __syncthreads();
#pragma unroll
  for (int i = 0; i < 16; ++i) mx = fmaxf(mx, sRa[i]);
  float sum = 0.f;
#pragma unroll
  for (int j = 0; j < 8; ++j) sum += expf(v[j] - mx);
#pragma unroll
  for (int m = 1; m < 64; m <<= 1) sum += __shfl_xor(sum, m, 64);
  if (lane == 0) sRb[w] = sum;
  __syncthreads();
  float tot = 0.f;
#pragma unroll
  for (int i = 0; i < 16; ++i) tot += sRb[i];
  float lse = logf(tot);
#pragma unroll
  for (int j = 0; j < 8; ++j) out[base + tid + j * 1024] = v[j] - mx - lse;
}

extern "C" void kernel_launch(void* const* d_in, const int* in_sizes, int n_in,
                              void* d_out, int out_size, void* d_ws, size_t ws_size,
                              hipStream_t stream) {
  const float* x  = (const float*)d_in[0];
  const float* Wg = (const float*)d_in[1];
  const float* W1 = (const float*)d_in[2];
  const float* b1 = (const float*)d_in[3];
  const float* W2 = (const float*)d_in[4];
  const float* b2 = (const float*)d_in[5];
  float* out = (float*)d_out;
  char* ws = (char*)d_ws;

  float*  w2s  = (float*)(ws);                          // 16 KB
  float*  vT   = (float*)(ws + (16u << 10));            // 16 KB
  float*  beta = (float*)(ws + (32u << 10));            // 32 B (padded)
  float*  dots = (float*)(ws + (64u << 10));            // 4 MB
  char*   p1   = ws + (64u << 10) + (4u << 20);
  float4* wd   = (float4*)(p1);                         // 1 MB
  int*    epk  = (int*)(p1 + (1u << 20));               // 256 KB
  int*    hist = (int*)(p1 + (1u << 20) + (256u << 10));// 16 KB
  int*    offa = (int*)(p1 + (1u << 20) + (272u << 10));// 16 KB
  float*  s    = (float*)(p1 + (1u << 20) + (288u << 10)); // 256 KB

  hipLaunchKernelGGL(k_w2s,    dim3(1024), dim3(256),  0, stream, W2, w2s);
  hipLaunchKernelGGL(k_v_beta, dim3(1025), dim3(256),  0, stream, W1, b1, b2, w2s, vT, beta);
  hipLaunchKernelGGL(k_dots,   dim3(1024), dim3(256),  0, stream, x, Wg, vT, dots);
  hipLaunchKernelGGL(k_top2,   dim3(256),  dim3(256),  0, stream, dots, beta, wd, epk, hist);
  hipLaunchKernelGGL(k_scan,   dim3(1),    dim3(256),  0, stream, hist, offa);
  hipLaunchKernelGGL(k_keep,   dim3(256),  dim3(256),  0, stream, epk, wd, offa, s);
  hipLaunchKernelGGL(k_lsm,    dim3(8),    dim3(1024), 0, stream, s, out);
}